// Round 6
// baseline (22227.646 us; speedup 1.0000x reference)
//
#include <hip/hip_runtime.h>
#include <stdint.h>
#include <stddef.h>

// ACT-LSTM, B=32 T=512 IN=50 H=512 OUT=66, MAX_PONDER=10, EPS=0.01, fp32.
// Round 6: same architecture as round 5 (decision-before-GEMM, replicated
// LDS accumulator, 2 phases/timestep, monotonic tree barrier, LLC-coherent
// h exchange, conflict-free LDS indexing) but 64 blocks x 512 threads:
// 2 waves/SIMD instead of 1 -> latency hiding via TLP for the L1 weight
// loads / LDS reads / LLC drain / barrier that dominated round 5's 85% stall.

#define NBLK 64

// ---------------- ws layout (float offsets) ----------------
// wh   : [0, 8388608)            512*32*512  (32 MB)
// hbuf : [8388608, 8421376)      2*16384     h ping-pong (packed [k4][b*4+kl])
// bar  : [8421376, 8421888)      512 uints   monotonic barrier counters
// W_r4 : [8421888, 9470464)      1048576     W_hh repacked [k4][j*16+g*4+kl]
// W_iT : [9470464, 9574912)      51*2048     W_ih repacked [k][j*4+g]
// W_oT : [9574912, 9608704)      512*66      W_out transposed [k][o]
#define WS_NEED_BYTES 38434816ull

__device__ __forceinline__ float sigmf(float v) { return 1.0f / (1.0f + expf(-v)); }

// LLC-coherent (cross-XCD) store: bypass L1+L2 (sc0 sc1).
__device__ __forceinline__ void store_llc(float* p, float v) {
  asm volatile("global_store_dword %0, %1, off sc0 sc1" :: "v"(p), "v"(v) : "memory");
}

#if defined(__has_builtin)
#if __has_builtin(__builtin_amdgcn_global_load_lds)
#define HAVE_GLLDS 1
#endif
#endif

// LLC-coherent global->LDS DMA, 16 B/lane. aux=0x11 = SC0|SC1.
__device__ __forceinline__ void stage_instr(const float* gp, float* lp) {
#ifdef HAVE_GLLDS
  __builtin_amdgcn_global_load_lds((const __attribute__((address_space(1))) unsigned int*)gp,
                                   (__attribute__((address_space(3))) unsigned int*)lp,
                                   16, 0, 0x11);
#else
  float4 tmp;
  asm volatile("global_load_dwordx4 %0, %1, off sc0 sc1" : "=v"(tmp) : "v"(gp) : "memory");
  asm volatile("s_waitcnt vmcnt(0)" ::: "memory");
  *(float4*)(lp + (threadIdx.x & 63) * 4) = tmp;
#endif
}

// ------------------------------------------------------------------
// prep: repack weights (k-major) + zero barrier words.
__global__ void prep_k(const float* __restrict__ W_ih, const float* __restrict__ W_hh,
                       const float* __restrict__ W_out,
                       float* __restrict__ W_r4, float* __restrict__ W_iT,
                       float* __restrict__ W_oT, unsigned* __restrict__ bar) {
  int idx = blockIdx.x * 256 + threadIdx.x;
  if (idx < 1048576) {
    int kl = idx & 3, g = (idx >> 2) & 3, j = (idx >> 4) & 511, k4 = idx >> 13;
    W_r4[idx] = W_hh[(size_t)((g << 9) + j) * 512 + (k4 << 2) + kl];
  }
  int i2 = idx - 1048576;
  if (i2 >= 0 && i2 < 104448) {
    int col = i2 & 2047, k = i2 >> 11;
    int g = col & 3, j = col >> 2;
    W_iT[i2] = W_ih[(size_t)((g << 9) + j) * 51 + k];
  }
  int i3 = idx - 1153024;
  if (i3 >= 0 && i3 < 33792) {
    int k = i3 / 66, o = i3 - k * 66;
    W_oT[i3] = W_out[(size_t)o * 512 + k];
  }
  int i4 = idx - 1186816;
  if (i4 >= 0 && i4 < 512) bar[i4] = 0u;
}

// ------------------------------------------------------------------
// persistent ACT-LSTM: 64 blocks x 512 threads (8 waves = 2/SIMD).
// Block owns j in [8*bid, 8*bid+8), all 4 gates = 32 dot-columns x 32 b.
// Thread (b_i = tid>>4, sub = tid&15): dot A = col (jj=sub>>2, g=sub&3),
// dot B = same gate, jj+4. 2 K=512 dots per thread per phase.
__global__ void __launch_bounds__(512)
act_main(const float* __restrict__ x, const float* __restrict__ bvec,
         const float* __restrict__ W_halt, const float* __restrict__ b_halt,
         const float* __restrict__ W_r4, const float* __restrict__ W_iT,
         float* __restrict__ hbuf, unsigned* __restrict__ bar,
         float* __restrict__ wh, float* __restrict__ p_out) {
  __shared__ float hch[16384];       // staged h2, 64 KB (packed [k4][b*4+kl])
  __shared__ float accL[16384];      // replicated weighted accumulator, 64 KB
  __shared__ float xch[2][512];      // gate exchange (dot A / dot B)
  __shared__ float hps[512];         // halt partials
  __shared__ float S_cum[32], S_p[32], S_nupd[32], S_rem[32];
  __shared__ int S_flag[1];          // alldone broadcast

  const int tid = threadIdx.x, bid = blockIdx.x;
  const int b_i = tid >> 4, sub = tid & 15;
  const int offw_a = bid * 128 + sub * 4;     // W_r4 dword offset (dot A); B at +64
  const int offi_a = bid * 32 + sub;          // W_iT dword offset (dot A); B at +16
  const int wid = tid >> 6, lane4 = (tid & 63) * 4;
  const int gA = sub & 3, jjA = sub >> 2;

  const float bias_a = bvec[gA * 512 + 8 * bid + jjA];
  const float bias_b = bvec[gA * 512 + 8 * bid + jjA + 4];
  const float bh = b_halt[0];
  const float wfa = W_iT[50 * 2048 + offi_a];      // first-step flag column
  const float wfb = W_iT[50 * 2048 + offi_a + 16];

  // owner lane (sub<8): owns (b_i, j = 8*bid + sub)
  const int hoidx = (2 * bid + (sub >> 2)) * 128 + b_i * 4 + (sub & 3);
  const float4* hch4 = (const float4*)hch;
  float4* acc4 = (float4*)accL;
  const float4* Wq = (const float4*)W_halt;   // [k4] float4 view

  // init shared state + zero accL (t=0's fresh GEMM reads accL as h=0)
  if (tid < 32) { S_cum[tid] = 0.f; S_nupd[tid] = 0.f; S_rem[tid] = 0.f; }
  {
    float4 z = {0.f, 0.f, 0.f, 0.f};
    #pragma unroll
    for (int i = 0; i < 8; ++i) acc4[i * 512 + tid] = z;
  }
  int mydone = 0;                     // per-decision-lane ACT done (tid<32)
  float cS = 0.f, acc_c = 0.f;
  float gxa, gxb2, gxn_a = 0.f, gxn_b = 0.f;
  {  // x-projection for t=0
    gxa = bias_a; gxb2 = bias_b;
    const float* xr = x + (size_t)b_i * 512 * 50;
    for (int k = 0; k < 50; ++k) {
      const float xv = xr[k];
      gxa  = fmaf(xv, W_iT[k * 2048 + offi_a], gxa);
      gxb2 = fmaf(xv, W_iT[k * 2048 + offi_a + 16], gxb2);
    }
  }
  int t = 0, n = 0, fresh = 1, first = 1;
  unsigned ph = 0;
  __syncthreads();

  while (true) {
    if (!first) {
      // ---- stage h2 of step (t,n) from buf[(ph-1)&1]: 8 KB/wave, one drain ----
      const float* hin = hbuf + (((ph & 1u) ^ 1u)) * 16384;
      {
        const float* gp = hin + wid * 2048 + lane4;
        float* lp = &hch[wid * 2048];
        #pragma unroll
        for (int q = 0; q < 8; ++q) stage_instr(gp + q * 256, lp + q * 256);
      }
      // hide DMA latency: precompute x-projection for t+1
      {
        const int tn = (t + 1 > 511) ? 511 : t + 1;
        gxn_a = bias_a; gxn_b = bias_b;
        const float* xr = x + ((size_t)b_i * 512 + tn) * 50;
        for (int k = 0; k < 50; ++k) {
          const float xv = xr[k];
          gxn_a = fmaf(xv, W_iT[k * 2048 + offi_a], gxn_a);
          gxn_b = fmaf(xv, W_iT[k * 2048 + offi_a + 16], gxn_b);
        }
      }
      asm volatile("s_waitcnt vmcnt(0)" ::: "memory");
      __syncthreads();

      // ---- halt partial: thread covers float4s f = i*512+tid (batch = tid&31),
      //      conflict-free contiguous-by-lane LDS reads ----
      {
        float hp = 0.f;
        #pragma unroll
        for (int i = 0; i < 8; ++i) {
          const int f = i * 512 + tid;
          const float4 hv = hch4[f];
          const float4 wv = Wq[f >> 5];
          hp = fmaf(hv.x, wv.x, fmaf(hv.y, wv.y, fmaf(hv.z, wv.z, fmaf(hv.w, wv.w, hp))));
        }
        hps[tid] = hp;
      }
      __syncthreads();

      // ---- ACT decision for step (t,n); ballot for alldone ----
      if (tid < 64) {
        int vote = 1;
        if (tid < 32) {
          float d = 0.f;
          #pragma unroll
          for (int r = 0; r < 16; ++r) d += hps[tid + 32 * r];  // distinct banks
          const float halt = sigmf(d + bh);
          const float cum = S_cum[tid];
          const int done = mydone;
          const int halted = ((cum + halt) > 0.99f) || (n == 9);
          S_p[tid] = done ? 0.f : (halted ? (1.f - cum) : halt);
          S_nupd[tid] += done ? 0.f : 1.f;
          S_rem[tid] += (done || !halted) ? 0.f : (1.f - cum);
          S_cum[tid] = cum + (done ? 0.f : halt);
          mydone = done | halted;
          vote = mydone;
        }
        const unsigned long long bal = __ballot(vote);
        if (tid == 0) S_flag[0] = (bal == ~0ull) ? 1 : 0;
      }
      __syncthreads();
      const int alldone = S_flag[0];

      // ---- accumulate: accL (+)= p_b * h2_staged, conflict-free indexing;
      //      n==0 overwrites (folds the zero pass) ----
      {
        const float p_t = S_p[tid & 31];
        if (n == 0) {
          #pragma unroll
          for (int i = 0; i < 8; ++i) {
            const int idx = i * 512 + tid;
            const float4 h = hch4[idx];
            float4 a;
            a.x = p_t * h.x; a.y = p_t * h.y; a.z = p_t * h.z; a.w = p_t * h.w;
            acc4[idx] = a;
          }
        } else {
          #pragma unroll
          for (int i = 0; i < 8; ++i) {
            const int idx = i * 512 + tid;
            float4 a = acc4[idx];
            const float4 h = hch4[idx];
            a.x = fmaf(p_t, h.x, a.x); a.y = fmaf(p_t, h.y, a.y);
            a.z = fmaf(p_t, h.z, a.z); a.w = fmaf(p_t, h.w, a.w);
            acc4[idx] = a;
          }
        }
      }
      if (sub < 8) acc_c = fmaf(S_p[b_i], cS, acc_c);  // c2 of staged step = cS

      if (alldone) {  // timestep t complete -> intra-phase carry
        __syncthreads();             // accL writes visible (GEMM + wh read it)
        if (sub < 8) {
          wh[(size_t)t * 16384 + (size_t)b_i * 512 + 8 * bid + sub] = accL[hoidx];
          cS = acc_c; acc_c = 0.f;
        }
        if (bid == 0 && tid < 32)
          p_out[(size_t)tid * 512 + t] = S_nupd[tid] + S_rem[tid];
        if (tid < 32) { S_cum[tid] = 0.f; S_nupd[tid] = 0.f; S_rem[tid] = 0.f; }
        mydone = 0;
        t += 1; n = 0; fresh = 1;
        gxa = gxn_a; gxb2 = gxn_b;
        if (t == 512) break;         // uniform across blocks
      } else {
        n += 1; fresh = 0;
      }
    }

    // ---- GEMM: input = accL (fresh/carry) or hch (continue) ----
    {
      const float base_a = gxa + (fresh ? wfa : 0.f);
      const float base_b = gxb2 + (fresh ? wfb : 0.f);
      const float* hl = fresh ? accL : hch;
      const float* hb = hl + b_i * 4;
      const float* wb = W_r4 + offw_a;
      float a0 = base_a, a1 = 0.f, a2 = 0.f, a3 = 0.f;
      float b0 = base_b, b1 = 0.f, b2 = 0.f, b3 = 0.f;
      #pragma unroll 8
      for (int u = 0; u < 128; ++u) {
        const float4 h4 = *(const float4*)(hb + u * 128);   // 16-lane broadcast
        const float4 wa = *(const float4*)(wb + (size_t)u * 8192);        // 256B/wave line
        const float4 wc = *(const float4*)(wb + (size_t)u * 8192 + 64);
        a0 = fmaf(h4.x, wa.x, a0); a1 = fmaf(h4.y, wa.y, a1);
        a2 = fmaf(h4.z, wa.z, a2); a3 = fmaf(h4.w, wa.w, a3);
        b0 = fmaf(h4.x, wc.x, b0); b1 = fmaf(h4.y, wc.y, b1);
        b2 = fmaf(h4.z, wc.z, b2); b3 = fmaf(h4.w, wc.w, b3);
      }
      xch[0][tid] = (a0 + a1) + (a2 + a3);
      xch[1][tid] = (b0 + b1) + (b2 + b3);
    }
    __syncthreads();

    if (sub < 8) {  // owner of (b_i, 8*bid+sub): gates -> h2, c2; publish h2
      const float* arr = (sub < 4) ? xch[0] : xch[1];
      const int base = b_i * 16 + (sub & 3) * 4;
      const float gi = arr[base + 0];
      const float gf = arr[base + 1];
      const float gg = arr[base + 2];
      const float go = arr[base + 3];
      const float c_new = sigmf(gf) * cS + sigmf(gi) * tanhf(gg);
      const float h_new = sigmf(go) * tanhf(c_new);
      store_llc(&hbuf[(ph & 1u) * 16384 + hoidx], h_new);
      cS = c_new;
    }
    first = 0; fresh = 0;

    // ---- grid barrier: monotonic counters, no resets; 64 arrivals ----
    asm volatile("s_waitcnt vmcnt(0)" ::: "memory");  // h2 stores at LLC
    __syncthreads();
    if (tid == 0) {
      const int grp = bid & 7;
      const unsigned a = __hip_atomic_fetch_add(&bar[grp * 32], 1u, __ATOMIC_RELAXED, __HIP_MEMORY_SCOPE_AGENT);
      if (a == ph * 8u + 7u) {
        const unsigned a2 = __hip_atomic_fetch_add(&bar[256], 1u, __ATOMIC_RELAXED, __HIP_MEMORY_SCOPE_AGENT);
        if (a2 == ph * 8u + 7u)
          __hip_atomic_store(&bar[288], ph + 1u, __ATOMIC_RELAXED, __HIP_MEMORY_SCOPE_AGENT);
      }
      while (__hip_atomic_load(&bar[288], __ATOMIC_RELAXED, __HIP_MEMORY_SCOPE_AGENT) < ph + 1u)
        __builtin_amdgcn_s_sleep(1);
    }
    __syncthreads();
    ph += 1;
  }
}

// ------------------------------------------------------------------
// epilogue: out[b,t,:] = seg-softmax(wh[t,b,:] @ W_out^T + b_out)
__global__ void __launch_bounds__(256)
epi_k(const float* __restrict__ wh, const float* __restrict__ W_oT,
      const float* __restrict__ b_out, float* __restrict__ out) {
  __shared__ float hl[4][512];
  __shared__ float yl[4][66];
  const int tid = threadIdx.x, pair = tid >> 6, lane = tid & 63;
  const int bt = blockIdx.x * 4 + pair;
  const int b = bt >> 9, t = bt & 511;
  const float* hsrc = wh + (size_t)t * 16384 + (size_t)b * 512;
  *(float4*)&hl[pair][lane * 8] = *(const float4*)(hsrc + lane * 8);
  *(float4*)&hl[pair][lane * 8 + 4] = *(const float4*)(hsrc + lane * 8 + 4);
  __syncthreads();
  if (lane < 33) {
    const int o = lane * 2;
    float y0 = b_out[o], y1 = b_out[o + 1];
    const float* hp_ = hl[pair];
    #pragma unroll 8
    for (int k = 0; k < 512; ++k) {
      const float h = hp_[k];
      const float2 w = *(const float2*)(W_oT + k * 66 + o);
      y0 = fmaf(h, w.x, y0);
      y1 = fmaf(h, w.y, y1);
    }
    yl[pair][o] = y0; yl[pair][o + 1] = y1;
  }
  __syncthreads();
  if (tid < 24) {
    const int pr = tid / 6, g = tid - pr * 6;
    const int bt2 = blockIdx.x * 4 + pr;
    const float* yp = &yl[pr][g * 11];
    float m = yp[0];
    for (int u = 1; u < 11; ++u) m = fmaxf(m, yp[u]);
    float e[11], ssum = 0.f;
    for (int u = 0; u < 11; ++u) { e[u] = expf(yp[u] - m); ssum += e[u]; }
    const float inv = 1.0f / ssum;
    float* op = out + (size_t)bt2 * 66 + g * 11;
    for (int u = 0; u < 11; ++u) op[u] = e[u] * inv;
  }
}

// ------------------------------------------------------------------
extern "C" void kernel_launch(void* const* d_in, const int* in_sizes, int n_in,
                              void* d_out, int out_size, void* d_ws, size_t ws_size,
                              hipStream_t stream) {
  (void)in_sizes; (void)n_in; (void)out_size;
  const float* x      = (const float*)d_in[0];
  const float* W_ih   = (const float*)d_in[1];
  const float* W_hh   = (const float*)d_in[2];
  const float* bvec   = (const float*)d_in[3];
  const float* W_out  = (const float*)d_in[4];
  const float* b_out  = (const float*)d_in[5];
  const float* W_halt = (const float*)d_in[6];
  const float* b_halt = (const float*)d_in[7];
  float* out = (float*)d_out;
  float* ws  = (float*)d_ws;

  if (ws_size < (size_t)WS_NEED_BYTES) return;  // visible failure if ws too small

  float* wh     = ws;
  float* hbuf   = ws + 8388608;
  unsigned* bar = (unsigned*)(ws + 8421376);
  float* W_r4   = ws + 8421888;
  float* W_iT   = ws + 9470464;
  float* W_oT   = ws + 9574912;
  float* p_out  = out + 1081344;  // B*T*OUT

  hipLaunchKernelGGL(prep_k, dim3(4638), dim3(256), 0, stream,
                     W_ih, W_hh, W_out, W_r4, W_iT, W_oT, bar);

  void* args[10];
  args[0] = (void*)&x;      args[1] = (void*)&bvec;  args[2] = (void*)&W_halt;
  args[3] = (void*)&b_halt; args[4] = (void*)&W_r4;  args[5] = (void*)&W_iT;
  args[6] = (void*)&hbuf;   args[7] = (void*)&bar;   args[8] = (void*)&wh;
  args[9] = (void*)&p_out;
  hipLaunchCooperativeKernel((void*)act_main, dim3(NBLK), dim3(512), args, 0, stream);

  hipLaunchKernelGGL(epi_k, dim3(4096), dim3(256), 0, stream, wh, W_oT, b_out, out);
}

// Round 7
// 13011.841 us; speedup vs baseline: 1.7083x; 1.7083x over previous
//
#include <hip/hip_runtime.h>
#include <stdint.h>
#include <stddef.h>

// ACT-LSTM, B=32 T=512 IN=50 H=512 OUT=66, MAX_PONDER=10, EPS=0.01, fp32.
// Round 7: linearity restructure. gAcc[4] = sum_n p_n*(W_hh @ h2_n) kept in
// owner registers, so the fresh-timestep gates = gx(t+1)+wf+gAcc need NO GEMM
// on the weighted accumulator: the per-phase GEMM always reads the staged h2
// and runs BEFORE the halt decision. accL (64KB LDS) and its accumulate pass
// are deleted; acc_h/acc_c live in owner registers. x-projection only on n==0
// phases (once per timestep), owner-centric, under the staging DMA.
// 128 blocks x 256 threads (R5's proven shape).

#define NBLK 128

// ---------------- ws layout (float offsets) ----------------
// wh   : [0, 8388608)            512*32*512  (32 MB)
// hbuf : [8388608, 8421376)      2*16384     h ping-pong (packed [k4][b*4+kl])
// bar  : [8421376, 8421888)      512 uints   monotonic barrier counters
// W_r4 : [8421888, 9470464)      1048576     W_hh repacked [k4][j*16+g*4+kl]
// W_iT : [9470464, 9574912)      51*2048     W_ih repacked [k][j*4+g]
// W_oT : [9574912, 9608704)      512*66      W_out transposed [k][o]
#define WS_NEED_BYTES 38434816ull

__device__ __forceinline__ float sigmf(float v) { return 1.0f / (1.0f + expf(-v)); }

// LLC-coherent (cross-XCD) store: bypass L1+L2 (sc0 sc1).
__device__ __forceinline__ void store_llc(float* p, float v) {
  asm volatile("global_store_dword %0, %1, off sc0 sc1" :: "v"(p), "v"(v) : "memory");
}

#if defined(__has_builtin)
#if __has_builtin(__builtin_amdgcn_global_load_lds)
#define HAVE_GLLDS 1
#endif
#endif

// LLC-coherent global->LDS DMA, 16 B/lane. aux=0x11 = SC0|SC1.
__device__ __forceinline__ void stage_instr(const float* gp, float* lp) {
#ifdef HAVE_GLLDS
  __builtin_amdgcn_global_load_lds((const __attribute__((address_space(1))) unsigned int*)gp,
                                   (__attribute__((address_space(3))) unsigned int*)lp,
                                   16, 0, 0x11);
#else
  float4 tmp;
  asm volatile("global_load_dwordx4 %0, %1, off sc0 sc1" : "=v"(tmp) : "v"(gp) : "memory");
  asm volatile("s_waitcnt vmcnt(0)" ::: "memory");
  *(float4*)(lp + (threadIdx.x & 63) * 4) = tmp;
#endif
}

// ------------------------------------------------------------------
// prep: repack weights (k-major) + zero barrier words.
__global__ void prep_k(const float* __restrict__ W_ih, const float* __restrict__ W_hh,
                       const float* __restrict__ W_out,
                       float* __restrict__ W_r4, float* __restrict__ W_iT,
                       float* __restrict__ W_oT, unsigned* __restrict__ bar) {
  int idx = blockIdx.x * 256 + threadIdx.x;
  if (idx < 1048576) {
    int kl = idx & 3, g = (idx >> 2) & 3, j = (idx >> 4) & 511, k4 = idx >> 13;
    W_r4[idx] = W_hh[(size_t)((g << 9) + j) * 512 + (k4 << 2) + kl];
  }
  int i2 = idx - 1048576;
  if (i2 >= 0 && i2 < 104448) {
    int col = i2 & 2047, k = i2 >> 11;
    int g = col & 3, j = col >> 2;
    W_iT[i2] = W_ih[(size_t)((g << 9) + j) * 51 + k];
  }
  int i3 = idx - 1153024;
  if (i3 >= 0 && i3 < 33792) {
    int k = i3 / 66, o = i3 - k * 66;
    W_oT[i3] = W_out[(size_t)o * 512 + k];
  }
  int i4 = idx - 1186816;
  if (i4 >= 0 && i4 < 512) bar[i4] = 0u;
}

// ------------------------------------------------------------------
// persistent ACT-LSTM: 128 blocks x 256 threads, 4 j-columns/block,
// 2 K=512 dots per thread per phase. Owner thread (sub<4) owns (b_i, 4bid+sub).
__global__ void __launch_bounds__(256)
act_main(const float* __restrict__ x, const float* __restrict__ bvec,
         const float* __restrict__ W_halt, const float* __restrict__ b_halt,
         const float* __restrict__ W_r4, const float* __restrict__ W_iT,
         float* __restrict__ hbuf, unsigned* __restrict__ bar,
         float* __restrict__ wh, float* __restrict__ p_out) {
  __shared__ float hch[16384];       // staged h2, 64 KB (packed [k4][b*4+kl])
  __shared__ float xch[2][256];      // gate-preact exchange (pure W_hh@h2)
  __shared__ float hps[256];         // halt partials
  __shared__ float S_cum[32], S_p[32], S_nupd[32], S_rem[32];
  __shared__ int S_flag[1];          // alldone broadcast

  const int tid = threadIdx.x, bid = blockIdx.x;
  const int b_i = tid >> 3, sub = tid & 7, jl = sub & 1, gate = sub >> 1;
  const int ja = bid * 4 + jl;
  const int offw_a = ja * 16 + gate * 4;      // W_r4 dword offset (dot A); B at +32
  const int wid = tid >> 6, lane4 = (tid & 63) * 4;
  const int jown = bid * 4 + sub;             // owner's j (valid when sub<4)
  const int hoidx = bid * 128 + b_i * 4 + sub;
  const float4* hch4 = (const float4*)hch;
  const float4* Wq = (const float4*)W_halt;   // [k4] float4 view

  const float bh = b_halt[0];

  // owner constants: flag column + biases for its 4 gates
  float wf0 = 0.f, wf1 = 0.f, wf2 = 0.f, wf3 = 0.f;
  float bs0 = 0.f, bs1 = 0.f, bs2 = 0.f, bs3 = 0.f;
  if (sub < 4) {
    const float4 wf = *(const float4*)(W_iT + 50 * 2048 + jown * 4);
    wf0 = wf.x; wf1 = wf.y; wf2 = wf.z; wf3 = wf.w;
    bs0 = bvec[jown]; bs1 = bvec[512 + jown]; bs2 = bvec[1024 + jown]; bs3 = bvec[1536 + jown];
  }

  // owner state
  float cS = 0.f, hprev = 0.f, acc_h = 0.f, acc_c = 0.f;
  float gA0 = 0.f, gA1 = 0.f, gA2 = 0.f, gA3 = 0.f;           // gAcc
  float gc0 = 0.f, gc1 = 0.f, gc2 = 0.f, gc3 = 0.f;           // gx(t)   (with bias)
  float gn0 = 0.f, gn1 = 0.f, gn2 = 0.f, gn3 = 0.f;           // gx(t+1) (with bias)
  if (sub < 4) {  // x-projection for t=0
    gc0 = bs0; gc1 = bs1; gc2 = bs2; gc3 = bs3;
    const float* xr = x + (size_t)b_i * 512 * 50;
    for (int k = 0; k < 50; ++k) {
      const float xv = xr[k];
      const float4 w = *(const float4*)(W_iT + k * 2048 + jown * 4);
      gc0 = fmaf(xv, w.x, gc0); gc1 = fmaf(xv, w.y, gc1);
      gc2 = fmaf(xv, w.z, gc2); gc3 = fmaf(xv, w.w, gc3);
    }
  }
  if (tid < 32) { S_cum[tid] = 0.f; S_nupd[tid] = 0.f; S_rem[tid] = 0.f; }
  int mydone = 0;
  int t = 0, n = 0, first = 1;
  unsigned ph = 0;
  __syncthreads();

  while (true) {
    if (first) {
      // ---- phase 0: compute step 0 of t=0 (h=0 -> gemm = 0) ----
      if (sub < 4) {
        const float c_new = sigmf(gc1 + wf1) * 0.f + sigmf(gc0 + wf0) * tanhf(gc2 + wf2);
        const float h_new = sigmf(gc3 + wf3) * tanhf(c_new);
        store_llc(&hbuf[hoidx], h_new);
        cS = c_new; hprev = h_new;
      }
      n = 0; first = 0;
    } else {
      // ---- stage h2 of staged step n from buf[(ph-1)&1] ----
      const float* hin = hbuf + ((ph & 1u) ^ 1u) * 16384;
      {
        const float* gp = hin + wid * 4096 + lane4;
        float* lp = &hch[wid * 4096];
        #pragma unroll
        for (int q = 0; q < 16; ++q) stage_instr(gp + q * 256, lp + q * 256);
      }
      // under the DMA: x-projection for t+1 (once per timestep, n==0 phase)
      if (n == 0 && sub < 4) {
        const int tn = (t + 1 > 511) ? 511 : t + 1;
        gn0 = bs0; gn1 = bs1; gn2 = bs2; gn3 = bs3;
        const float* xr = x + ((size_t)b_i * 512 + tn) * 50;
        for (int k = 0; k < 50; ++k) {
          const float xv = xr[k];
          const float4 w = *(const float4*)(W_iT + k * 2048 + jown * 4);
          gn0 = fmaf(xv, w.x, gn0); gn1 = fmaf(xv, w.y, gn1);
          gn2 = fmaf(xv, w.z, gn2); gn3 = fmaf(xv, w.w, gn3);
        }
      }
      asm volatile("s_waitcnt vmcnt(0)" ::: "memory");
      __syncthreads();

      // ---- GEMM (pure W_hh @ h2, decision-independent) ----
      {
        const float* hb = hch + b_i * 4;
        const float* wb = W_r4 + offw_a;
        float a0 = 0.f, a1 = 0.f, a2 = 0.f, a3 = 0.f;
        float b0 = 0.f, b1 = 0.f, b2 = 0.f, b3 = 0.f;
        #pragma unroll 8
        for (int u = 0; u < 128; ++u) {
          const float4 h4 = *(const float4*)(hb + u * 128);   // 8-lane broadcast
          const float4 wa = *(const float4*)(wb + (size_t)u * 8192);
          const float4 wc = *(const float4*)(wb + (size_t)u * 8192 + 32);
          a0 = fmaf(h4.x, wa.x, a0); a1 = fmaf(h4.y, wa.y, a1);
          a2 = fmaf(h4.z, wa.z, a2); a3 = fmaf(h4.w, wa.w, a3);
          b0 = fmaf(h4.x, wc.x, b0); b1 = fmaf(h4.y, wc.y, b1);
          b2 = fmaf(h4.z, wc.z, b2); b3 = fmaf(h4.w, wc.w, b3);
        }
        xch[0][tid] = (a0 + a1) + (a2 + a3);
        xch[1][tid] = (b0 + b1) + (b2 + b3);
      }
      // ---- halt partials (conflict-free contiguous-by-lane) ----
      {
        float hp = 0.f;
        #pragma unroll
        for (int i = 0; i < 16; ++i) {
          const int f = i * 256 + tid;
          const float4 hv = hch4[f];
          const float4 wv = Wq[f >> 5];
          hp = fmaf(hv.x, wv.x, fmaf(hv.y, wv.y, fmaf(hv.z, wv.z, fmaf(hv.w, wv.w, hp))));
        }
        hps[tid] = hp;
      }
      __syncthreads();

      // ---- ACT decision for staged step n; ballot alldone ----
      if (tid < 64) {
        int vote = 1;
        if (tid < 32) {
          float d = 0.f;
          #pragma unroll
          for (int r = 0; r < 8; ++r) d += hps[tid + 32 * r];
          const float halt = sigmf(d + bh);
          const float cum = S_cum[tid];
          const int done = mydone;
          const int halted = ((cum + halt) > 0.99f) || (n == 9);
          S_p[tid] = done ? 0.f : (halted ? (1.f - cum) : halt);
          S_nupd[tid] += done ? 0.f : 1.f;
          S_rem[tid] += (done || !halted) ? 0.f : (1.f - cum);
          S_cum[tid] = cum + (done ? 0.f : halt);
          mydone = done | halted;
          vote = mydone;
        }
        const unsigned long long bal = __ballot(vote);
        if (tid == 0) S_flag[0] = (bal == ~0ull) ? 1 : 0;
      }
      __syncthreads();
      const int alldone = S_flag[0];

      // ---- owner combine: accumulate + one cell step ----
      float g0 = 0.f, g1 = 0.f, g2 = 0.f, g3 = 0.f, p = 0.f;
      if (sub < 4) {
        const float* arr = (sub < 2) ? xch[0] : xch[1];
        const int jjl = sub & 1;
        g0 = arr[b_i * 8 + jjl];          // gate i
        g1 = arr[b_i * 8 + 2 + jjl];      // gate f
        g2 = arr[b_i * 8 + 4 + jjl];      // gate g
        g3 = arr[b_i * 8 + 6 + jjl];      // gate o
        p = S_p[b_i];
        gA0 = fmaf(p, g0, gA0); gA1 = fmaf(p, g1, gA1);
        gA2 = fmaf(p, g2, gA2); gA3 = fmaf(p, g3, gA3);
        acc_h = fmaf(p, hprev, acc_h);
        acc_c = fmaf(p, cS, acc_c);
      }

      if (alldone) {  // timestep t ends; fresh step of t+1 in the same phase
        if (sub < 4)
          wh[(size_t)t * 16384 + (size_t)b_i * 512 + jown] = acc_h;
        if (bid == 0 && tid < 32)
          p_out[(size_t)tid * 512 + t] = S_nupd[tid] + S_rem[tid];
        if (tid < 32) { S_cum[tid] = 0.f; S_nupd[tid] = 0.f; S_rem[tid] = 0.f; }
        mydone = 0;
        t += 1; n = 0;
        if (t == 512) break;        // uniform (deterministic replicated decisions)
        if (sub < 4) {              // fresh gates = gx(t) + wf + gAcc (no GEMM!)
          const float c_new = sigmf(gn1 + wf1 + gA1) * acc_c +
                              sigmf(gn0 + wf0 + gA0) * tanhf(gn2 + wf2 + gA2);
          const float h_new = sigmf(gn3 + wf3 + gA3) * tanhf(c_new);
          store_llc(&hbuf[(ph & 1u) * 16384 + hoidx], h_new);
          cS = c_new; hprev = h_new;
          acc_h = 0.f; acc_c = 0.f;
          gA0 = 0.f; gA1 = 0.f; gA2 = 0.f; gA3 = 0.f;
          gc0 = gn0; gc1 = gn1; gc2 = gn2; gc3 = gn3;
        }
      } else {        // continue: step n+1 gates = gx(t) + gemm
        if (sub < 4) {
          const float c_new = sigmf(gc1 + g1) * cS + sigmf(gc0 + g0) * tanhf(gc2 + g2);
          const float h_new = sigmf(gc3 + g3) * tanhf(c_new);
          store_llc(&hbuf[(ph & 1u) * 16384 + hoidx], h_new);
          cS = c_new; hprev = h_new;
        }
        n += 1;
      }
    }

    // ---- grid barrier: monotonic counters, no resets ----
    asm volatile("s_waitcnt vmcnt(0)" ::: "memory");  // h2 stores at LLC
    __syncthreads();
    if (tid == 0) {
      const int grp = bid & 7;
      const unsigned a = __hip_atomic_fetch_add(&bar[grp * 32], 1u, __ATOMIC_RELAXED, __HIP_MEMORY_SCOPE_AGENT);
      if (a == ph * 16u + 15u) {
        const unsigned a2 = __hip_atomic_fetch_add(&bar[256], 1u, __ATOMIC_RELAXED, __HIP_MEMORY_SCOPE_AGENT);
        if (a2 == ph * 8u + 7u)
          __hip_atomic_store(&bar[288], ph + 1u, __ATOMIC_RELAXED, __HIP_MEMORY_SCOPE_AGENT);
      }
      while (__hip_atomic_load(&bar[288], __ATOMIC_RELAXED, __HIP_MEMORY_SCOPE_AGENT) < ph + 1u)
        __builtin_amdgcn_s_sleep(2);
    }
    __syncthreads();
    ph += 1;
  }
}

// ------------------------------------------------------------------
// epilogue: out[b,t,:] = seg-softmax(wh[t,b,:] @ W_out^T + b_out)
__global__ void __launch_bounds__(256)
epi_k(const float* __restrict__ wh, const float* __restrict__ W_oT,
      const float* __restrict__ b_out, float* __restrict__ out) {
  __shared__ float hl[4][512];
  __shared__ float yl[4][66];
  const int tid = threadIdx.x, pair = tid >> 6, lane = tid & 63;
  const int bt = blockIdx.x * 4 + pair;
  const int b = bt >> 9, t = bt & 511;
  const float* hsrc = wh + (size_t)t * 16384 + (size_t)b * 512;
  *(float4*)&hl[pair][lane * 8] = *(const float4*)(hsrc + lane * 8);
  *(float4*)&hl[pair][lane * 8 + 4] = *(const float4*)(hsrc + lane * 8 + 4);
  __syncthreads();
  if (lane < 33) {
    const int o = lane * 2;
    float y0 = b_out[o], y1 = b_out[o + 1];
    const float* hp_ = hl[pair];
    #pragma unroll 8
    for (int k = 0; k < 512; ++k) {
      const float h = hp_[k];
      const float2 w = *(const float2*)(W_oT + k * 66 + o);
      y0 = fmaf(h, w.x, y0);
      y1 = fmaf(h, w.y, y1);
    }
    yl[pair][o] = y0; yl[pair][o + 1] = y1;
  }
  __syncthreads();
  if (tid < 24) {
    const int pr = tid / 6, g = tid - pr * 6;
    const int bt2 = blockIdx.x * 4 + pr;
    const float* yp = &yl[pr][g * 11];
    float m = yp[0];
    for (int u = 1; u < 11; ++u) m = fmaxf(m, yp[u]);
    float e[11], ssum = 0.f;
    for (int u = 0; u < 11; ++u) { e[u] = expf(yp[u] - m); ssum += e[u]; }
    const float inv = 1.0f / ssum;
    float* op = out + (size_t)bt2 * 66 + g * 11;
    for (int u = 0; u < 11; ++u) op[u] = e[u] * inv;
  }
}

// ------------------------------------------------------------------
extern "C" void kernel_launch(void* const* d_in, const int* in_sizes, int n_in,
                              void* d_out, int out_size, void* d_ws, size_t ws_size,
                              hipStream_t stream) {
  (void)in_sizes; (void)n_in; (void)out_size;
  const float* x      = (const float*)d_in[0];
  const float* W_ih   = (const float*)d_in[1];
  const float* W_hh   = (const float*)d_in[2];
  const float* bvec   = (const float*)d_in[3];
  const float* W_out  = (const float*)d_in[4];
  const float* b_out  = (const float*)d_in[5];
  const float* W_halt = (const float*)d_in[6];
  const float* b_halt = (const float*)d_in[7];
  float* out = (float*)d_out;
  float* ws  = (float*)d_ws;

  if (ws_size < (size_t)WS_NEED_BYTES) return;  // visible failure if ws too small

  float* wh     = ws;
  float* hbuf   = ws + 8388608;
  unsigned* bar = (unsigned*)(ws + 8421376);
  float* W_r4   = ws + 8421888;
  float* W_iT   = ws + 9470464;
  float* W_oT   = ws + 9574912;
  float* p_out  = out + 1081344;  // B*T*OUT

  hipLaunchKernelGGL(prep_k, dim3(4638), dim3(256), 0, stream,
                     W_ih, W_hh, W_out, W_r4, W_iT, W_oT, bar);

  void* args[10];
  args[0] = (void*)&x;      args[1] = (void*)&bvec;  args[2] = (void*)&W_halt;
  args[3] = (void*)&b_halt; args[4] = (void*)&W_r4;  args[5] = (void*)&W_iT;
  args[6] = (void*)&hbuf;   args[7] = (void*)&bar;   args[8] = (void*)&wh;
  args[9] = (void*)&p_out;
  hipLaunchCooperativeKernel((void*)act_main, dim3(NBLK), dim3(256), args, 0, stream);

  hipLaunchKernelGGL(epi_k, dim3(4096), dim3(256), 0, stream, wh, W_oT, b_out, out);
}